// Round 4
// baseline (769.380 us; speedup 1.0000x reference)
//
#include <hip/hip_runtime.h>
#include <math.h>

#define N_NODES 50000
#define N_EDGES 800000
#define NFEAT   512
#define NHID    64
#define NCLASS  40

// ---------------------------------------------------------------------------
// CSR build: histogram of dst -> exclusive scan -> scatter of edge ids into
// perm[], so SpMM is a per-row gather-reduce with NO fp atomics.
// ---------------------------------------------------------------------------

__global__ void zero_kernel(int* __restrict__ p, int n) {
    int i = blockIdx.x * blockDim.x + threadIdx.x;
    if (i < n) p[i] = 0;
}

__global__ void hist_kernel(const int* __restrict__ dst, int* __restrict__ counts) {
    int i = blockIdx.x * blockDim.x + threadIdx.x;
    if (i < N_EDGES) atomicAdd(&counts[dst[i]], 1);
}

// Single 1024-thread block: thread t serially sums a 49-row chunk, Hillis-
// Steele scan of the 1024 partials in LDS, then writes the exclusive prefix
// back over its chunk (into row_off and the scatter cursor, which aliases
// the counts buffer).
__global__ __launch_bounds__(1024) void scan_kernel(int* __restrict__ cnt_next,
                                                    int* __restrict__ row_off) {
    __shared__ int lds[1024];
    const int t  = threadIdx.x;
    const int CH = (N_NODES + 1023) / 1024;      // 49
    const int lo = t * CH;
    const int hi = (lo + CH < N_NODES) ? lo + CH : N_NODES;

    int s = 0;
    for (int i = lo; i < hi; ++i) s += cnt_next[i];
    lds[t] = s;
    __syncthreads();
    for (int off = 1; off < 1024; off <<= 1) {
        int v = (t >= off) ? lds[t - off] : 0;
        __syncthreads();
        lds[t] += v;
        __syncthreads();
    }
    int excl  = lds[t] - s;
    int total = lds[1023];

    int run = excl;
    for (int i = lo; i < hi; ++i) {
        int c = cnt_next[i];          // read before overwrite (same buffer)
        row_off[i]  = run;
        cnt_next[i] = run;            // becomes the scatter cursor
        run += c;
    }
    if (t == 0) row_off[N_NODES] = total;
}

__global__ void scatter_kernel(const int* __restrict__ dst,
                               int* __restrict__ cursor,
                               int* __restrict__ perm) {
    int i = blockIdx.x * blockDim.x + threadIdx.x;
    if (i < N_EDGES) {
        int p = atomicAdd(&cursor[dst[i]], 1);
        perm[p] = i;
    }
}

// ---------------------------------------------------------------------------
// GEMM1: xw = x @ W1.  [50000,512] x [512,64].
// Wave-per-8-rows, lane = output column. W1 staged in LDS pre-swizzled so the
// inner loop does one conflict-free ds_read_b128 per 4 k-steps. K is split in
// FOUR 128-wide quarters (32 KB LDS each -- stays well under the 64 KB
// per-workgroup edge case); partial sums carried through xw (L2-resident).
// ---------------------------------------------------------------------------
#define KQ 128                         // k-extent per quarter
#define KG (KQ / 4)                    // 32 float4-groups per quarter

__global__ __launch_bounds__(1024) void gemm1_kernel(const float* __restrict__ x,
                                                     const float* __restrict__ W1,
                                                     float* __restrict__ xw) {
    __shared__ float4 wlds[KG * NHID];  // 32*64 float4 = 32 KB
    const int tid  = threadIdx.x;
    const int lane = tid & 63;
    const int R    = 8;
    const int ngroups = (N_NODES + R - 1) / R;       // 6250
    const int gwid = blockIdx.x * 16 + (tid >> 6);
    const int nw   = gridDim.x * 16;

    for (int quarter = 0; quarter < 4; ++quarter) {
        __syncthreads();                              // previous quarter's reads done
        for (int idx = tid; idx < KG * NHID; idx += 1024) {
            int k0 = idx >> 6;
            int c  = idx & 63;
            int kb = quarter * KQ + 4 * k0;
            float4 v;
            v.x = W1[(kb + 0) * NHID + c];
            v.y = W1[(kb + 1) * NHID + c];
            v.z = W1[(kb + 2) * NHID + c];
            v.w = W1[(kb + 3) * NHID + c];
            wlds[idx] = v;
        }
        __syncthreads();

        for (int g = gwid; g < ngroups; g += nw) {
            const int row0 = g * R;
            float acc[R];
            const float* xp[R];
#pragma unroll
            for (int r = 0; r < R; ++r) {
                acc[r] = 0.f;
                int row = row0 + r; if (row > N_NODES - 1) row = N_NODES - 1;
                xp[r] = x + (size_t)row * NFEAT + quarter * KQ;
            }
#pragma unroll 2
            for (int k0 = 0; k0 < KG; ++k0) {
                float4 w4 = wlds[k0 * 64 + lane];
#pragma unroll
                for (int r = 0; r < R; ++r) {
                    float4 xv = *reinterpret_cast<const float4*>(xp[r] + 4 * k0);
                    acc[r] = fmaf(xv.x, w4.x,
                             fmaf(xv.y, w4.y,
                             fmaf(xv.z, w4.z,
                             fmaf(xv.w, w4.w, acc[r]))));
                }
            }
#pragma unroll
            for (int r = 0; r < R; ++r) {
                int row = row0 + r;
                if (row < N_NODES) {
                    float* p = &xw[(size_t)row * NHID + lane];
                    if (quarter == 0) *p = acc[r];
                    else              *p += acc[r];
                }
            }
        }
    }
}

// ---------------------------------------------------------------------------
// SpMM1 + bias + relu: h[r] = relu(sum_e val_e * xw[src_e] + b1)
// Wave per row, lane = feature (64). 4-way unrolled gather for ILP.
// ---------------------------------------------------------------------------
__global__ void spmm1_kernel(const float* __restrict__ xw,
                             const float* __restrict__ adj_vals,
                             const int* __restrict__ src,
                             const int* __restrict__ perm,
                             const int* __restrict__ row_off,
                             const float* __restrict__ b1,
                             float* __restrict__ h) {
    const int lane = threadIdx.x & 63;
    const int row  = blockIdx.x * 4 + (threadIdx.x >> 6);
    if (row >= N_NODES) return;
    const int lo = row_off[row], hi = row_off[row + 1];
    float acc = 0.f;
    int i = lo;
    for (; i + 3 < hi; i += 4) {
        int e0 = perm[i], e1 = perm[i+1], e2 = perm[i+2], e3 = perm[i+3];
        float v0 = adj_vals[e0], v1 = adj_vals[e1], v2 = adj_vals[e2], v3 = adj_vals[e3];
        int s0 = src[e0], s1 = src[e1], s2 = src[e2], s3 = src[e3];
        float f0 = xw[s0*NHID+lane], f1 = xw[s1*NHID+lane];
        float f2 = xw[s2*NHID+lane], f3 = xw[s3*NHID+lane];
        acc += v0*f0; acc += v1*f1; acc += v2*f2; acc += v3*f3;
    }
    for (; i < hi; ++i) {
        int e = perm[i];
        acc += adj_vals[e] * xw[src[e]*NHID + lane];
    }
    h[(size_t)row * NHID + lane] = fmaxf(acc + b1[lane], 0.f);
}

// ---------------------------------------------------------------------------
// GEMM2: hw = h @ W2. [50000,64] x [64,40]. Same broadcast scheme, W2 in LDS.
// ---------------------------------------------------------------------------
__global__ void gemm2_kernel(const float* __restrict__ h,
                             const float* __restrict__ W2,
                             float* __restrict__ hw) {
    __shared__ float4 wlds[(NHID / 4) * NCLASS];   // 16*40 float4 = 10 KB
    const int tid = threadIdx.x;
    for (int idx = tid; idx < (NHID / 4) * NCLASS; idx += 256) {
        int k0 = idx / NCLASS, c = idx % NCLASS;
        float4 v;
        v.x = W2[(4*k0 + 0) * NCLASS + c];
        v.y = W2[(4*k0 + 1) * NCLASS + c];
        v.z = W2[(4*k0 + 2) * NCLASS + c];
        v.w = W2[(4*k0 + 3) * NCLASS + c];
        wlds[idx] = v;
    }
    __syncthreads();

    const int R = 8;
    const int lane = tid & 63;
    const int wid  = blockIdx.x * 4 + (tid >> 6);
    const int ngroups = (N_NODES + R - 1) / R;
    if (wid >= ngroups) return;
    const int row0 = wid * R;
    const int cl = (lane < NCLASS) ? lane : (NCLASS - 1);
    const bool active = lane < NCLASS;

    float acc[R];
    const float* hp[R];
#pragma unroll
    for (int r = 0; r < R; ++r) {
        acc[r] = 0.f;
        int row = row0 + r; if (row > N_NODES - 1) row = N_NODES - 1;
        hp[r] = h + (size_t)row * NHID;
    }
#pragma unroll
    for (int k0 = 0; k0 < NHID / 4; ++k0) {
        float4 w4 = wlds[k0 * NCLASS + cl];
#pragma unroll
        for (int r = 0; r < R; ++r) {
            float4 hv = *reinterpret_cast<const float4*>(hp[r] + 4 * k0);
            acc[r] = fmaf(hv.x, w4.x,
                     fmaf(hv.y, w4.y,
                     fmaf(hv.z, w4.z,
                     fmaf(hv.w, w4.w, acc[r]))));
        }
    }
#pragma unroll
    for (int r = 0; r < R; ++r) {
        int row = row0 + r;
        if (active && row < N_NODES) hw[(size_t)row * NCLASS + lane] = acc[r];
    }
}

// ---------------------------------------------------------------------------
// SpMM2 + b2 + log_softmax, fused. Wave per row, lanes 0..39 = classes.
// Max and sum via 64-lane shfl butterflies (inactive lanes neutralized).
// ---------------------------------------------------------------------------
__global__ void spmm2_lsm_kernel(const float* __restrict__ hw,
                                 const float* __restrict__ adj_vals,
                                 const int* __restrict__ src,
                                 const int* __restrict__ perm,
                                 const int* __restrict__ row_off,
                                 const float* __restrict__ b2,
                                 float* __restrict__ out) {
    const int lane = threadIdx.x & 63;
    const int row  = blockIdx.x * 4 + (threadIdx.x >> 6);
    if (row >= N_NODES) return;
    const bool active = lane < NCLASS;
    const int cl = active ? lane : (NCLASS - 1);
    const int lo = row_off[row], hi = row_off[row + 1];
    float acc = 0.f;
    int i = lo;
    for (; i + 3 < hi; i += 4) {
        int e0 = perm[i], e1 = perm[i+1], e2 = perm[i+2], e3 = perm[i+3];
        float v0 = adj_vals[e0], v1 = adj_vals[e1], v2 = adj_vals[e2], v3 = adj_vals[e3];
        int s0 = src[e0], s1 = src[e1], s2 = src[e2], s3 = src[e3];
        float f0 = hw[s0*NCLASS+cl], f1 = hw[s1*NCLASS+cl];
        float f2 = hw[s2*NCLASS+cl], f3 = hw[s3*NCLASS+cl];
        acc += v0*f0; acc += v1*f1; acc += v2*f2; acc += v3*f3;
    }
    for (; i < hi; ++i) {
        int e = perm[i];
        acc += adj_vals[e] * hw[src[e]*NCLASS + cl];
    }
    float logit = acc + b2[cl];
    float m = active ? logit : -INFINITY;
#pragma unroll
    for (int o = 32; o > 0; o >>= 1) m = fmaxf(m, __shfl_xor(m, o));
    float ex = active ? expf(logit - m) : 0.f;
    float ssum = ex;
#pragma unroll
    for (int o = 32; o > 0; o >>= 1) ssum += __shfl_xor(ssum, o);
    if (active) out[(size_t)row * NCLASS + lane] = logit - m - logf(ssum);
}

// ---------------------------------------------------------------------------

extern "C" void kernel_launch(void* const* d_in, const int* in_sizes, int n_in,
                              void* d_out, int out_size, void* d_ws, size_t ws_size,
                              hipStream_t stream) {
    const float* x        = (const float*)d_in[0];
    const float* adj_vals = (const float*)d_in[1];
    const float* W1       = (const float*)d_in[2];
    const float* b1       = (const float*)d_in[3];
    const float* W2       = (const float*)d_in[4];
    const float* b2       = (const float*)d_in[5];
    const int*   src      = (const int*)d_in[6];
    const int*   dst      = (const int*)d_in[7];
    float* out = (float*)d_out;

    // Workspace layout (29.2 MB total). hw aliases xw: xw is dead after
    // spmm1_kernel completes, and gemm2_kernel (which writes hw) launches
    // after it on the same stream.
    const size_t OFF_H    = 12800000;            // h   : 50000*64 f32
    const size_t OFF_ROFF = 25600000;            // row_off: 50001 ints
    const size_t OFF_CUR  = 25800016;            // cursor : 50000 ints
    const size_t OFF_PERM = 26000016;            // perm   : 800000 ints
    const size_t REQUIRED = OFF_PERM + (size_t)N_EDGES * 4;  // 29,200,016 B

    // Defensive: if the harness workspace is smaller than our layout, do
    // nothing rather than write OOB and kill the GPU. (ws_size is constant
    // across calls, so this branch is graph-capture-deterministic.)
    if (ws_size < REQUIRED) return;

    char* ws = (char*)d_ws;
    float* xw      = (float*)(ws);
    float* hw      = (float*)(ws);               // alias of xw (see above)
    float* h       = (float*)(ws + OFF_H);
    int*   row_off = (int*)  (ws + OFF_ROFF);
    int*   cursor  = (int*)  (ws + OFF_CUR);
    int*   perm    = (int*)  (ws + OFF_PERM);

    // CSR build (ws is poisoned 0xAA each call -> zero the counters first)
    zero_kernel<<<(N_NODES + 255) / 256, 256, 0, stream>>>(cursor, N_NODES);
    hist_kernel<<<(N_EDGES + 255) / 256, 256, 0, stream>>>(dst, cursor);
    scan_kernel<<<1, 1024, 0, stream>>>(cursor, row_off);
    scatter_kernel<<<(N_EDGES + 255) / 256, 256, 0, stream>>>(dst, cursor, perm);

    // Dense + sparse pipeline
    gemm1_kernel<<<512, 1024, 0, stream>>>(x, W1, xw);
    spmm1_kernel<<<(N_NODES + 3) / 4, 256, 0, stream>>>(xw, adj_vals, src, perm, row_off, b1, h);
    gemm2_kernel<<<((N_NODES + 7) / 8 + 3) / 4, 256, 0, stream>>>(h, W2, hw);
    spmm2_lsm_kernel<<<(N_NODES + 3) / 4, 256, 0, stream>>>(hw, adj_vals, src, perm, row_off, b2, out);
}

// Round 5
// 577.901 us; speedup vs baseline: 1.3313x; 1.3313x over previous
//
#include <hip/hip_runtime.h>
#include <math.h>

#define N_NODES 50000
#define N_EDGES 800000
#define NFEAT   512
#define NHID    64
#define NCLASS  40

// ---------------------------------------------------------------------------
// CSR build: histogram of dst -> exclusive scan -> scatter of edge ids into
// perm[], so SpMM is a per-row gather-reduce with NO fp atomics.
// ---------------------------------------------------------------------------

__global__ void zero_kernel(int* __restrict__ p, int n) {
    int i = blockIdx.x * blockDim.x + threadIdx.x;
    if (i < n) p[i] = 0;
}

__global__ void hist_kernel(const int* __restrict__ dst, int* __restrict__ counts) {
    int i = blockIdx.x * blockDim.x + threadIdx.x;
    if (i < N_EDGES) atomicAdd(&counts[dst[i]], 1);
}

__global__ __launch_bounds__(1024) void scan_kernel(int* __restrict__ cnt_next,
                                                    int* __restrict__ row_off) {
    __shared__ int lds[1024];
    const int t  = threadIdx.x;
    const int CH = (N_NODES + 1023) / 1024;      // 49
    const int lo = t * CH;
    const int hi = (lo + CH < N_NODES) ? lo + CH : N_NODES;

    int s = 0;
    for (int i = lo; i < hi; ++i) s += cnt_next[i];
    lds[t] = s;
    __syncthreads();
    for (int off = 1; off < 1024; off <<= 1) {
        int v = (t >= off) ? lds[t - off] : 0;
        __syncthreads();
        lds[t] += v;
        __syncthreads();
    }
    int excl  = lds[t] - s;
    int total = lds[1023];

    int run = excl;
    for (int i = lo; i < hi; ++i) {
        int c = cnt_next[i];          // read before overwrite (same buffer)
        row_off[i]  = run;
        cnt_next[i] = run;            // becomes the scatter cursor
        run += c;
    }
    if (t == 0) row_off[N_NODES] = total;
}

__global__ void scatter_kernel(const int* __restrict__ dst,
                               int* __restrict__ cursor,
                               int* __restrict__ perm) {
    int i = blockIdx.x * blockDim.x + threadIdx.x;
    if (i < N_EDGES) {
        int p = atomicAdd(&cursor[dst[i]], 1);
        perm[p] = i;
    }
}

// ---------------------------------------------------------------------------
// GEMM1: xw = x @ W1.  [50000,512] x [512,64].
// Block = 256 threads (4 waves), block tile = 64 rows x 64 cols.
// Lane tile = 4 rows x 4 cols (acc[4][4] in regs, carried across ALL of K:
// no xw read-modify-write). W1 staged per 128-k chunk in LDS (32 KB),
// bank-swizzled so each of a lane's 4 col-reads is a conflict-free
// ds_read_b128 (lane-consecutive 16B addresses):
//   slot(k0, col) = k0*64 + (col&3)*16 + (col>>2)
// so instruction c has lane i16 reading slot k0*64 + c*16 + i16 -> holds
// col 4*i16 + c. Lane's cols = [4*i16, 4*i16+3] -> float4 store of xw.
// x is read straight from global: 4 distinct 16B broadcast addresses per
// instr (one per 16-lane row group); unroll 4 keeps ~16 loads in flight.
// ---------------------------------------------------------------------------
__global__ __launch_bounds__(256) void gemm1_kernel(const float* __restrict__ x,
                                                    const float* __restrict__ W1,
                                                    float* __restrict__ xw) {
    __shared__ float4 wlds[32 * 64];              // 32 KB per 128-k chunk
    const int tid  = threadIdx.x;
    const int lane = tid & 63;
    const int i16  = lane & 15;                   // col group: cols 4*i16..+3
    const int rg   = lane >> 4;                   // row group within wave (0..3)
    const int wave = tid >> 6;                    // 0..3

    const int block_row0 = blockIdx.x * 64;
    const int wave_row0  = block_row0 + wave * 16;

    // Per-lane row bases (clamped for the tail block; stores are guarded).
    const float* xb[4];
    int rows[4];
#pragma unroll
    for (int r = 0; r < 4; ++r) {
        int row = wave_row0 + rg * 4 + r;
        rows[r] = row;
        int rc = row < N_NODES ? row : N_NODES - 1;
        xb[r] = x + (size_t)rc * NFEAT;
    }

    float acc[4][4];
#pragma unroll
    for (int r = 0; r < 4; ++r)
#pragma unroll
        for (int c = 0; c < 4; ++c) acc[r][c] = 0.f;

    for (int chunk = 0; chunk < 4; ++chunk) {
        __syncthreads();                          // previous chunk's reads done
        // Stage W1[kb..kb+127][0..63] -> wlds, swizzled. 2048 float4s, 256 thr.
        for (int idx = tid; idx < 32 * 64; idx += 256) {
            int k0  = idx >> 6;
            int col = idx & 63;
            int kb  = chunk * 128 + 4 * k0;
            float4 v;
            v.x = W1[(kb + 0) * NHID + col];
            v.y = W1[(kb + 1) * NHID + col];
            v.z = W1[(kb + 2) * NHID + col];
            v.w = W1[(kb + 3) * NHID + col];
            wlds[k0 * 64 + (col & 3) * 16 + (col >> 2)] = v;
        }
        __syncthreads();

        const int kb = chunk * 128;
#pragma unroll 4
        for (int k0 = 0; k0 < 32; ++k0) {
            float4 wv[4];
#pragma unroll
            for (int c = 0; c < 4; ++c)
                wv[c] = wlds[k0 * 64 + c * 16 + i16];
#pragma unroll
            for (int r = 0; r < 4; ++r) {
                float4 xv = *reinterpret_cast<const float4*>(xb[r] + kb + 4 * k0);
#pragma unroll
                for (int c = 0; c < 4; ++c) {
                    acc[r][c] = fmaf(xv.x, wv[c].x,
                                fmaf(xv.y, wv[c].y,
                                fmaf(xv.z, wv[c].z,
                                fmaf(xv.w, wv[c].w, acc[r][c]))));
                }
            }
        }
    }

    // Epilogue: one float4 store per row (cols 4*i16..4*i16+3 consecutive).
#pragma unroll
    for (int r = 0; r < 4; ++r) {
        if (rows[r] < N_NODES) {
            float4 o; o.x = acc[r][0]; o.y = acc[r][1]; o.z = acc[r][2]; o.w = acc[r][3];
            *reinterpret_cast<float4*>(&xw[(size_t)rows[r] * NHID + 4 * i16]) = o;
        }
    }
}

// ---------------------------------------------------------------------------
// SpMM1 + bias + relu: h[r] = relu(sum_e val_e * xw[src_e] + b1)
// Wave per row, lane = feature (64). 4-way unrolled gather for ILP.
// ---------------------------------------------------------------------------
__global__ void spmm1_kernel(const float* __restrict__ xw,
                             const float* __restrict__ adj_vals,
                             const int* __restrict__ src,
                             const int* __restrict__ perm,
                             const int* __restrict__ row_off,
                             const float* __restrict__ b1,
                             float* __restrict__ h) {
    const int lane = threadIdx.x & 63;
    const int row  = blockIdx.x * 4 + (threadIdx.x >> 6);
    if (row >= N_NODES) return;
    const int lo = row_off[row], hi = row_off[row + 1];
    float acc = 0.f;
    int i = lo;
    for (; i + 3 < hi; i += 4) {
        int e0 = perm[i], e1 = perm[i+1], e2 = perm[i+2], e3 = perm[i+3];
        float v0 = adj_vals[e0], v1 = adj_vals[e1], v2 = adj_vals[e2], v3 = adj_vals[e3];
        int s0 = src[e0], s1 = src[e1], s2 = src[e2], s3 = src[e3];
        float f0 = xw[s0*NHID+lane], f1 = xw[s1*NHID+lane];
        float f2 = xw[s2*NHID+lane], f3 = xw[s3*NHID+lane];
        acc += v0*f0; acc += v1*f1; acc += v2*f2; acc += v3*f3;
    }
    for (; i < hi; ++i) {
        int e = perm[i];
        acc += adj_vals[e] * xw[src[e]*NHID + lane];
    }
    h[(size_t)row * NHID + lane] = fmaxf(acc + b1[lane], 0.f);
}

// ---------------------------------------------------------------------------
// GEMM2: hw = h @ W2. [50000,64] x [64,40]. Broadcast scheme, W2 in LDS.
// ---------------------------------------------------------------------------
__global__ void gemm2_kernel(const float* __restrict__ h,
                             const float* __restrict__ W2,
                             float* __restrict__ hw) {
    __shared__ float4 wlds[(NHID / 4) * NCLASS];   // 16*40 float4 = 10 KB
    const int tid = threadIdx.x;
    for (int idx = tid; idx < (NHID / 4) * NCLASS; idx += 256) {
        int k0 = idx / NCLASS, c = idx % NCLASS;
        float4 v;
        v.x = W2[(4*k0 + 0) * NCLASS + c];
        v.y = W2[(4*k0 + 1) * NCLASS + c];
        v.z = W2[(4*k0 + 2) * NCLASS + c];
        v.w = W2[(4*k0 + 3) * NCLASS + c];
        wlds[idx] = v;
    }
    __syncthreads();

    const int R = 8;
    const int lane = tid & 63;
    const int wid  = blockIdx.x * 4 + (tid >> 6);
    const int ngroups = (N_NODES + R - 1) / R;
    if (wid >= ngroups) return;
    const int row0 = wid * R;
    const int cl = (lane < NCLASS) ? lane : (NCLASS - 1);
    const bool active = lane < NCLASS;

    float acc[R];
    const float* hp[R];
#pragma unroll
    for (int r = 0; r < R; ++r) {
        acc[r] = 0.f;
        int row = row0 + r; if (row > N_NODES - 1) row = N_NODES - 1;
        hp[r] = h + (size_t)row * NHID;
    }
#pragma unroll
    for (int k0 = 0; k0 < NHID / 4; ++k0) {
        float4 w4 = wlds[k0 * NCLASS + cl];
#pragma unroll
        for (int r = 0; r < R; ++r) {
            float4 hv = *reinterpret_cast<const float4*>(hp[r] + 4 * k0);
            acc[r] = fmaf(hv.x, w4.x,
                     fmaf(hv.y, w4.y,
                     fmaf(hv.z, w4.z,
                     fmaf(hv.w, w4.w, acc[r]))));
        }
    }
#pragma unroll
    for (int r = 0; r < R; ++r) {
        int row = row0 + r;
        if (active && row < N_NODES) hw[(size_t)row * NCLASS + lane] = acc[r];
    }
}

// ---------------------------------------------------------------------------
// SpMM2 + b2 + log_softmax, fused. Wave per row, lanes 0..39 = classes.
// ---------------------------------------------------------------------------
__global__ void spmm2_lsm_kernel(const float* __restrict__ hw,
                                 const float* __restrict__ adj_vals,
                                 const int* __restrict__ src,
                                 const int* __restrict__ perm,
                                 const int* __restrict__ row_off,
                                 const float* __restrict__ b2,
                                 float* __restrict__ out) {
    const int lane = threadIdx.x & 63;
    const int row  = blockIdx.x * 4 + (threadIdx.x >> 6);
    if (row >= N_NODES) return;
    const bool active = lane < NCLASS;
    const int cl = active ? lane : (NCLASS - 1);
    const int lo = row_off[row], hi = row_off[row + 1];
    float acc = 0.f;
    int i = lo;
    for (; i + 3 < hi; i += 4) {
        int e0 = perm[i], e1 = perm[i+1], e2 = perm[i+2], e3 = perm[i+3];
        float v0 = adj_vals[e0], v1 = adj_vals[e1], v2 = adj_vals[e2], v3 = adj_vals[e3];
        int s0 = src[e0], s1 = src[e1], s2 = src[e2], s3 = src[e3];
        float f0 = hw[s0*NCLASS+cl], f1 = hw[s1*NCLASS+cl];
        float f2 = hw[s2*NCLASS+cl], f3 = hw[s3*NCLASS+cl];
        acc += v0*f0; acc += v1*f1; acc += v2*f2; acc += v3*f3;
    }
    for (; i < hi; ++i) {
        int e = perm[i];
        acc += adj_vals[e] * hw[src[e]*NCLASS + cl];
    }
    float logit = acc + b2[cl];
    float m = active ? logit : -INFINITY;
#pragma unroll
    for (int o = 32; o > 0; o >>= 1) m = fmaxf(m, __shfl_xor(m, o));
    float ex = active ? expf(logit - m) : 0.f;
    float ssum = ex;
#pragma unroll
    for (int o = 32; o > 0; o >>= 1) ssum += __shfl_xor(ssum, o);
    if (active) out[(size_t)row * NCLASS + lane] = logit - m - logf(ssum);
}

// ---------------------------------------------------------------------------

extern "C" void kernel_launch(void* const* d_in, const int* in_sizes, int n_in,
                              void* d_out, int out_size, void* d_ws, size_t ws_size,
                              hipStream_t stream) {
    const float* x        = (const float*)d_in[0];
    const float* adj_vals = (const float*)d_in[1];
    const float* W1       = (const float*)d_in[2];
    const float* b1       = (const float*)d_in[3];
    const float* W2       = (const float*)d_in[4];
    const float* b2       = (const float*)d_in[5];
    const int*   src      = (const int*)d_in[6];
    const int*   dst      = (const int*)d_in[7];
    float* out = (float*)d_out;

    // Workspace layout (29.2 MB, known-good). hw aliases xw (xw dead after
    // spmm1; gemm2 launches after it on the same stream).
    const size_t OFF_H    = 12800000;
    const size_t OFF_ROFF = 25600000;
    const size_t OFF_CUR  = 25800016;
    const size_t OFF_PERM = 26000016;
    const size_t REQUIRED = OFF_PERM + (size_t)N_EDGES * 4;  // 29,200,016 B
    if (ws_size < REQUIRED) return;

    char* ws = (char*)d_ws;
    float* xw      = (float*)(ws);
    float* hw      = (float*)(ws);               // alias of xw (see above)
    float* h       = (float*)(ws + OFF_H);
    int*   row_off = (int*)  (ws + OFF_ROFF);
    int*   cursor  = (int*)  (ws + OFF_CUR);
    int*   perm    = (int*)  (ws + OFF_PERM);

    // CSR build (ws is poisoned 0xAA each call -> zero the counters first)
    zero_kernel<<<(N_NODES + 255) / 256, 256, 0, stream>>>(cursor, N_NODES);
    hist_kernel<<<(N_EDGES + 255) / 256, 256, 0, stream>>>(dst, cursor);
    scan_kernel<<<1, 1024, 0, stream>>>(cursor, row_off);
    scatter_kernel<<<(N_EDGES + 255) / 256, 256, 0, stream>>>(dst, cursor, perm);

    // Dense + sparse pipeline
    gemm1_kernel<<<(N_NODES + 63) / 64, 256, 0, stream>>>(x, W1, xw);
    spmm1_kernel<<<(N_NODES + 3) / 4, 256, 0, stream>>>(xw, adj_vals, src, perm, row_off, b1, h);
    gemm2_kernel<<<((N_NODES + 7) / 8 + 3) / 4, 256, 0, stream>>>(h, W2, hw);
    spmm2_lsm_kernel<<<(N_NODES + 3) / 4, 256, 0, stream>>>(hw, adj_vals, src, perm, row_off, b2, out);
}